// Round 10
// baseline (334.501 us; speedup 1.0000x reference)
//
#include <hip/hip_runtime.h>
#include <hip/hip_bf16.h>

// Problem: B=8, T=256, V=32, D=256.
// Per-v GEMM: M=N=2048 (rows = i*T+q / j*T+k), K=256, then exp + 3 reductions.
// feature[B,T,V,D]: element (row, v, d) at feat[(row*32 + v)*256 + d].
// v10 = v9 with the B-repack FUSED into main behind a software grid barrier:
//  - v9 lesson: B-repack (27us) and main's A-prologue (~19us) are both pure
//    streaming and ran back-to-back with zero overlap across a kernel
//    boundary. Fusing merges them into one streaming phase feeding the sweep.
//  - grid (16,32) = 512 blocks = EXACTLY 2/CU capacity (launch_bounds(256,2),
//    64KB LDS) -> all blocks co-resident -> software grid barrier is safe
//    (guide §1/§6 G16: device-scope atomics + declared occupancy).
//  - Barrier: per-wave vmcnt(0) + threadfence + syncthreads; one agent-scope
//    ACQ_REL fetch-add; spin on agent ACQUIRE load until 512; syncthreads +
//    threadfence (acquire invalidate also kills stale pB lines from the
//    previous graph replay). Counter zeroed each replay by the init kernel.
//  - Phases per block: A-prologue (v9, verified) -> repack own 4 B rows ->
//    grid barrier -> stage B0/B1 -> v5b counted-vmcnt N-sweep (verbatim).

typedef __attribute__((ext_vector_type(4))) float f32x4;
typedef __attribute__((ext_vector_type(4))) int   i32x4;
typedef __attribute__((ext_vector_type(8))) int   i32x8;
typedef __attribute__((ext_vector_type(8))) __bf16 bf16x8;   // fallback path

#if __has_builtin(__builtin_amdgcn_exp2f)
#define EXP2(x) __builtin_amdgcn_exp2f(x)
#else
#define EXP2(x) exp2f(x)
#endif

#define LOG2E 1.4426950408889634f

#define WAIT_VMCNT(N)                                              \
    do {                                                           \
        asm volatile("s_waitcnt vmcnt(" #N ")" ::: "memory");      \
        __builtin_amdgcn_sched_barrier(0);                         \
    } while (0)
#define WAIT_LGKM0                                                 \
    do {                                                           \
        asm volatile("s_waitcnt lgkmcnt(0)" ::: "memory");         \
        __builtin_amdgcn_sched_barrier(0);                         \
    } while (0)
#define BARRIER()                                                  \
    do {                                                           \
        __builtin_amdgcn_s_barrier();                              \
        __builtin_amdgcn_sched_barrier(0);                         \
    } while (0)

__device__ __forceinline__ unsigned short f2bf(float f) {
    unsigned u = __builtin_bit_cast(unsigned, f);
    u += 0x7FFFu + ((u >> 16) & 1u);   // RNE (no NaNs in data)
    return (unsigned short)(u >> 16);
}

template <bool HI>
__device__ __forceinline__ unsigned cvt2fp8(float a, float b, unsigned old) {
    return __builtin_amdgcn_cvt_pk_fp8_f32(a, b, old, HI);
}
__device__ __forceinline__ unsigned pack4fp8(float x, float y, float z, float w) {
    return cvt2fp8<true>(z, w, cvt2fp8<false>(x, y, 0u));
}

__device__ __forceinline__ void async16(const void* g, void* l) {
    __builtin_amdgcn_global_load_lds(
        (const __attribute__((address_space(1))) unsigned int*)g,
        (__attribute__((address_space(3))) unsigned int*)l,
        16, 0, 0);
}

__device__ __forceinline__ i32x8 cat8(i32x4 lo, i32x4 hi) {
    i32x8 r;
    r[0] = lo[0]; r[1] = lo[1]; r[2] = lo[2]; r[3] = lo[3];
    r[4] = hi[0]; r[5] = hi[1]; r[6] = hi[2]; r[7] = hi[3];
    return r;
}

// DPP row-sum over 16-lane rows; full sum lands in lane 15 of each row.
template <int CTRL>
__device__ __forceinline__ float dpp_add(float x) {
    int y = __builtin_amdgcn_update_dpp(0, __builtin_bit_cast(int, x),
                                        CTRL, 0xf, 0xf, true);
    return x + __builtin_bit_cast(float, y);
}
__device__ __forceinline__ float rowsum16(float x) {
    x = dpp_add<0x111>(x);   // row_shr:1
    x = dpp_add<0x112>(x);   // row_shr:2
    x = dpp_add<0x114>(x);   // row_shr:4
    x = dpp_add<0x118>(x);   // row_shr:8
    return x;
}

// ------------- init: zero counters + grid-barrier slot (every replay) -------
__global__ __launch_bounds__(256) void infonce_init(
    float* __restrict__ counters, unsigned* __restrict__ bar)
{
    const int tid = threadIdx.x;
    #pragma unroll
    for (int k = 0; k < 24; ++k) counters[k * 256 + tid] = 0.f;
    if (tid == 0) *bar = 0u;
}

// ----- fused main: A-convert + B-repack + grid barrier + N-sweep ------------
// block = (tileM 0..15, v 0..31). A: fp32 staged through a 32 KB LDS buffer
// (4 chunks of 32 rows), converted in-LDS to prescaled fp8 frags in regs.
// B: this block repacks rows [lin*4, lin*4+4) fp32->fp8 into pB, then after
// the grid barrier runs the counted-vmcnt sweep on pB. 64 KB LDS, 2 blk/CU.
__global__ __launch_bounds__(256, 2) void infonce_fused(
    const float* __restrict__ feat, const float* __restrict__ feat_aug,
    unsigned char* __restrict__ pB, float* __restrict__ total,
    float* __restrict__ selfp, float* __restrict__ ap,
    unsigned* __restrict__ bar)
{
    __shared__ __align__(16) unsigned char Stage[32 * 1024];   // fp32 A chunks
    __shared__ __align__(16) unsigned char Bs[2][64 * 256];
    // scratch aliases Stage after the final loop barrier (A frags in regs)
    float (*ls_row2)[128]  = (float (*)[128])(void*)Stage;
    float (*ls_self2)[128] = (float (*)[128])(void*)(Stage + 1024);

    const int tid  = threadIdx.x;
    const int lane = tid & 63;
    const int w    = tid >> 6;        // wave 0..3
    const int wm   = w >> 1;          // A rows half
    const int wn   = w & 1;           // B cols half (within 64-col tile)
    const int lrow = lane & 15;
    const int quad = lane >> 4;

    const int tileM = blockIdx.x;     // 0..15
    const int v     = blockIdx.y;     // 0..31
    const int nD0   = (tileM >> 1) * 4;   // first diagonal n-iter

    const size_t vOff = (size_t)v * 256;

    // ---- phase 1: A tile fp32 -> LDS (coalesced, swizzled) -> fp8 frags ----
    // (v9 path, verified bit-identical to the old repack+LDS pipeline.)
    i32x8 af[2][4];   // [k-half][m-tile]
    #pragma unroll
    for (int c = 0; c < 4; ++c) {
        #pragma unroll
        for (int i = 0; i < 8; ++i) {
            const int rl = w * 8 + i;                     // chunk-local row
            const int gr = tileM * 128 + c * 32 + rl;     // global A row
            const int sg = lane ^ (rl & 15);              // source 16B group
            async16((const unsigned char*)feat +
                        ((size_t)gr * 8192 + vOff + (size_t)sg * 4) * 4,
                    &Stage[rl * 1024 + lane * 16]);
        }
        WAIT_VMCNT(0);     // chunk staged
        BARRIER();
        if ((c >> 1) == wm) {
            #pragma unroll
            for (int tt = 0; tt < 2; ++tt) {
                const int t  = (c & 1) * 2 + tt;          // compile-time
                const int rl = tt * 16 + lrow;            // local row
                #pragma unroll
                for (int h = 0; h < 2; ++h) {
                    i32x8 r;
                    #pragma unroll
                    for (int j = 0; j < 8; ++j) {
                        const int G = h * 32 + quad * 8 + j;   // global group
                        const float4 f = *(const float4*)
                            &Stage[rl * 1024 + ((G ^ lrow) * 16)];
                        r[j] = pack4fp8(f.x * LOG2E, f.y * LOG2E,
                                        f.z * LOG2E, f.w * LOG2E);
                    }
                    af[h][t] = r;
                }
            }
        }
        WAIT_LGKM0;        // my Stage reads done before next chunk overwrites
        BARRIER();
    }

    // ---- phase 2: repack this block's 4 B rows (fp32 -> fp8, unscaled) ----
    {
        const int lin = blockIdx.x + 16 * blockIdx.y;     // 0..511
        #pragma unroll
        for (int rr = 0; rr < 4; ++rr) {
            const size_t row = (size_t)(lin * 4 + rr);
            const float* srcR = feat_aug + row * 8192;
            unsigned char* dstR = pB + row * 8192;
            #pragma unroll
            for (int it = 0; it < 8; ++it) {
                const int o = (it * 256 + tid) * 4;       // float offset
                const float4 f = *(const float4*)(srcR + o);
                *(unsigned*)(dstR + o) = pack4fp8(f.x, f.y, f.z, f.w);
            }
        }
    }

    // ---- phase 3: grid barrier (all 512 blocks resident by construction) ---
    WAIT_VMCNT(0);            // my loads AND pB stores retired
    __threadfence();          // release: make pB stores visible device-wide
    __syncthreads();          // all waves of this block done + fenced
    if (tid == 0) {
        __hip_atomic_fetch_add(bar, 1u, __ATOMIC_ACQ_REL,
                               __HIP_MEMORY_SCOPE_AGENT);
        unsigned got;
        do {
            __builtin_amdgcn_s_sleep(4);
            got = __hip_atomic_load(bar, __ATOMIC_ACQUIRE,
                                    __HIP_MEMORY_SCOPE_AGENT);
        } while (got < 512u);
    }
    __syncthreads();
    __threadfence();          // acquire: invalidate stale pB lines (incl.
                              // previous graph-replay contents)

    // ---- phase 4: stage B tiles 0,1 and run the counted-vmcnt N-sweep ------
    const size_t rowNbase = (size_t)(w * 16 + quad) * 8192 + vOff;
    #pragma unroll
    for (int nn = 0; nn < 2; ++nn) {
        const unsigned char* srcB = pB + rowNbase + (size_t)nn * 64 * 8192;
        #pragma unroll
        for (int i = 0; i < 4; ++i) {
            const int lg = (lrow ^ ((i * 4 + quad) & 15)) << 4;
            async16(srcB + (size_t)i * 4 * 8192 + lg,
                    &Bs[nn][(w * 16 + i * 4) * 256]);
        }
    }
    // 8 outstanding; iter 0's WAIT_VMCNT(4) gates on B0 landed, B1 in flight.

    float rowp[4][4];   // row partials, all n
    float selfr[4][4];  // row partials, diagonal n only
    #pragma unroll
    for (int t = 0; t < 4; ++t)
        #pragma unroll
        for (int r = 0; r < 4; ++r) { rowp[t][r] = 0.f; selfr[t][r] = 0.f; }

    // Per-iteration body AFTER the vmcnt gate. Block-uniform branches only.
    auto iterBody = [&](const int n) {
        const int b = n & 1;
        BARRIER();                      // all waves: Bs[b] contents valid

        // ---- read ALL B fragments of this tile (8 x ds_read_b128) ----
        i32x8 bfr[2][2];                // [k-half][tj]
        #pragma unroll
        for (int h = 0; h < 2; ++h)
            #pragma unroll
            for (int tj = 0; tj < 2; ++tj) {
                const int rB = (wn * 32 + tj * 16 + lrow) * 256;
                const int g0 = ((h * 8 + quad * 2) ^ lrow) * 16;
                bfr[h][tj] = cat8(*(const i32x4*)&Bs[b][rB + g0],
                                  *(const i32x4*)&Bs[b][rB + (g0 ^ 16)]);
            }
        WAIT_LGKM0;                     // my reads of Bs[b] complete
        BARRIER();                      // everyone's reads done -> overwritable

        if (n < 30) {                   // stage tile n+2 into Bs[b]
            const unsigned char* src = pB + rowNbase + (size_t)(n + 2) * 64 * 8192;
            #pragma unroll
            for (int i = 0; i < 4; ++i) {
                const int lg = (lrow ^ ((i * 4 + quad) & 15)) << 4;
                async16(src + (size_t)i * 4 * 8192 + lg,
                        &Bs[b][(w * 16 + i * 4) * 256]);
            }
        }

        // ---- MFMA (regs only) ----
        f32x4 acc[4][2];
        #pragma unroll
        for (int t = 0; t < 4; ++t)
            #pragma unroll
            for (int tj = 0; tj < 2; ++tj)
                acc[t][tj] = (f32x4){0.f, 0.f, 0.f, 0.f};
        __builtin_amdgcn_s_setprio(1);
        #pragma unroll
        for (int h = 0; h < 2; ++h)
            #pragma unroll
            for (int ti = 0; ti < 4; ++ti)
                #pragma unroll
                for (int tj = 0; tj < 2; ++tj)
                    acc[ti][tj] = __builtin_amdgcn_mfma_scale_f32_16x16x128_f8f6f4(
                        af[h][ti], bfr[h][tj], acc[ti][tj],
                        0, 0, 0, 127, 0, 127);   // fp8/fp8, unit E8M0 scales
        __builtin_amdgcn_s_setprio(0);

        // ---- epilogue-accumulate: E = exp2(acc) (A prescaled by log2 e) ----
        const bool diagIter = (n >= nD0) && (n < nD0 + 4);
        float colp0 = 0.f, colp1 = 0.f;
        #pragma unroll
        for (int t = 0; t < 4; ++t)
            #pragma unroll
            for (int r = 0; r < 4; ++r) {
                float e0 = EXP2(acc[t][0][r]);
                float e1 = EXP2(acc[t][1][r]);
                rowp[t][r] += e0 + e1;
                if (diagIter) { selfr[t][r] += e0 + e1; colp0 += e0; colp1 += e1; }
            }
        if (diagIter) {   // col sums -> ap (wave-uniform branch, 4 of 32 iters)
            float q0 = colp0, q1 = colp1;
            q0 += __shfl_xor(q0, 16); q0 += __shfl_xor(q0, 32);
            q1 += __shfl_xor(q1, 16); q1 += __shfl_xor(q1, 32);
            if (lane < 16) {
                atomicAdd(&ap[n * 64 + wn * 32 + lane], q0);
                atomicAdd(&ap[n * 64 + wn * 32 + 16 + lane], q1);
            }
        }
        // no per-iter vmcnt drain: next iter's WAIT_VMCNT is the only gate
    };

    for (int n = 0; n < 31; ++n) {
        // Steady state: outstanding = tiles n (issued at n-2) + n+1 (at n-1);
        // wait(4) -> tile n landed.
        WAIT_VMCNT(4);
        iterBody(n);
    }
    WAIT_VMCNT(0);       // last tile: drain everything
    iterBody(31);

    // ---- final row reductions: DPP over the 16 cols held per lane-row ----
    #pragma unroll
    for (int t = 0; t < 4; ++t)
        #pragma unroll
        for (int r = 0; r < 4; ++r) {
            float rs = rowsum16(rowp[t][r]);
            float ss = rowsum16(selfr[t][r]);
            if (lrow == 15) {
                const int idx = wm * 64 + t * 16 + quad * 4 + r;
                ls_row2[wn][idx]  = rs;
                ls_self2[wn][idx] = ss;
            }
        }
    __syncthreads();
    if (tid < 128) {
        atomicAdd(&total[tileM * 128 + tid], ls_row2[0][tid] + ls_row2[1][tid]);
    } else {
        const int t2 = tid - 128;
        atomicAdd(&selfp[tileM * 128 + t2], ls_self2[0][t2] + ls_self2[1][t2]);
    }
}

// ---------------- fallback main (round-1 kernel, fp32 staging) ---------------
__global__ __launch_bounds__(256) void infonce_main_slow(
    const float* __restrict__ feat, const float* __restrict__ feat_aug,
    float* __restrict__ total, float* __restrict__ selfp, float* __restrict__ ap)
{
    __shared__ __align__(16) unsigned short As[128][72];
    __shared__ __align__(16) unsigned short Bs[128][72];
    __shared__ float ls_row[128];
    __shared__ float ls_col[128];

    const int tid  = threadIdx.x;
    const int lane = tid & 63;
    const int w    = tid >> 6;
    const int wm   = w >> 1;
    const int wn   = w & 1;
    const int lrow = lane & 15;
    const int quad = lane >> 4;

    const int tileM = blockIdx.x & 15;
    const int tileN = blockIdx.x >> 4;
    const int v     = blockIdx.y;
    const bool diag = (tileM >> 1) == (tileN >> 1);

    if (tid < 128) ls_row[tid] = 0.0f;
    else           ls_col[tid - 128] = 0.0f;

    const float* aBase = feat     + (size_t)v * 256;
    const float* bBase = feat_aug + (size_t)v * 256;

    f32x4 acc[4][4];
    #pragma unroll
    for (int i = 0; i < 4; ++i)
        #pragma unroll
        for (int j = 0; j < 4; ++j)
            acc[i][j] = (f32x4){0.f, 0.f, 0.f, 0.f};

    const int srow = tid >> 4;
    const int scol = (tid & 15) * 4;

    for (int s = 0; s < 4; ++s) {
        const int k0 = s * 64;
        if (s) __syncthreads();
        #pragma unroll
        for (int it = 0; it < 8; ++it) {
            const int row = it * 16 + srow;
            const float4 a4 = *(const float4*)(aBase + (size_t)(tileM * 128 + row) * 8192 + k0 + scol);
            const float4 b4 = *(const float4*)(bBase + (size_t)(tileN * 128 + row) * 8192 + k0 + scol);
            uint2 wa, wb;
            wa.x = (unsigned)f2bf(a4.x) | ((unsigned)f2bf(a4.y) << 16);
            wa.y = (unsigned)f2bf(a4.z) | ((unsigned)f2bf(a4.w) << 16);
            wb.x = (unsigned)f2bf(b4.x) | ((unsigned)f2bf(b4.y) << 16);
            wb.y = (unsigned)f2bf(b4.z) | ((unsigned)f2bf(b4.w) << 16);
            *(uint2*)&As[row][scol] = wa;
            *(uint2*)&Bs[row][scol] = wb;
        }
        __syncthreads();
        #pragma unroll
        for (int kk = 0; kk < 64; kk += 32) {
            bf16x8 af[4], bfr[4];
            #pragma unroll
            for (int t = 0; t < 4; ++t) {
                af[t]  = *(const bf16x8*)&As[wm * 64 + t * 16 + lrow][kk + quad * 8];
                bfr[t] = *(const bf16x8*)&Bs[wn * 64 + t * 16 + lrow][kk + quad * 8];
            }
            #pragma unroll
            for (int ti = 0; ti < 4; ++ti)
                #pragma unroll
                for (int tj = 0; tj < 4; ++tj)
                    acc[ti][tj] = __builtin_amdgcn_mfma_f32_16x16x32_bf16(
                        af[ti], bfr[tj], acc[ti][tj], 0, 0, 0);
        }
    }

    float colp[4] = {0.f, 0.f, 0.f, 0.f};
    #pragma unroll
    for (int ti = 0; ti < 4; ++ti) {
        #pragma unroll
        for (int r = 0; r < 4; ++r) {
            float e0 = __expf(acc[ti][0][r]);
            float e1 = __expf(acc[ti][1][r]);
            float e2 = __expf(acc[ti][2][r]);
            float e3 = __expf(acc[ti][3][r]);
            colp[0] += e0; colp[1] += e1; colp[2] += e2; colp[3] += e3;
            float rp = (e0 + e1) + (e2 + e3);
            rp += __shfl_xor(rp, 1);
            rp += __shfl_xor(rp, 2);
            rp += __shfl_xor(rp, 4);
            rp += __shfl_xor(rp, 8);
            if (lrow == 0)
                atomicAdd(&ls_row[wm * 64 + ti * 16 + quad * 4 + r], rp);
        }
    }
    if (diag) {
        #pragma unroll
        for (int tj = 0; tj < 4; ++tj) {
            float q = colp[tj];
            q += __shfl_xor(q, 16);
            q += __shfl_xor(q, 32);
            if (lane < 16)
                atomicAdd(&ls_col[wn * 64 + tj * 16 + lane], q);
        }
    }
    __syncthreads();
    if (tid < 128) {
        const float rs = ls_row[tid];
        const int rowg = tileM * 128 + tid;
        atomicAdd(&total[rowg], rs);
        if (diag) atomicAdd(&selfp[rowg], rs);
    } else if (diag) {
        const int t2 = tid - 128;
        atomicAdd(&ap[tileN * 128 + t2], ls_col[t2]);
    }
}

__global__ __launch_bounds__(256) void infonce_finalize(
    const float* __restrict__ total, const float* __restrict__ selfp,
    const float* __restrict__ ap, float* __restrict__ out)
{
    __shared__ float red[4];
    const int tid = threadIdx.x;
    float s = 0.f;
    for (int e = tid; e < 2048; e += 256) {
        const float an = total[e] - selfp[e];
        s += logf(an / ap[e]);
    }
    #pragma unroll
    for (int m = 32; m >= 1; m >>= 1) s += __shfl_xor(s, m);
    if ((tid & 63) == 0) red[tid >> 6] = s;
    __syncthreads();
    if (tid == 0) out[0] = (red[0] + red[1] + red[2] + red[3]) * (1.0f / 256.0f);
}

extern "C" void kernel_launch(void* const* d_in, const int* in_sizes, int n_in,
                              void* d_out, int out_size, void* d_ws, size_t ws_size,
                              hipStream_t stream) {
    const float* feat     = (const float*)d_in[0];
    const float* feat_aug = (const float*)d_in[1];
    float* total = (float*)d_ws;
    float* selfp = total + 2048;
    float* ap    = selfp + 2048;
    unsigned* bar = (unsigned*)(ap + 2048);

    const size_t packBytes = (size_t)2048 * 8192;                  // B tensor, fp8
    const size_t need = 32768 + packBytes;
    if (ws_size >= need) {
        unsigned char* pB = (unsigned char*)d_ws + 32768;
        infonce_init<<<dim3(1), 256, 0, stream>>>(total, bar);
        infonce_fused<<<dim3(16, 32), 256, 0, stream>>>(
            feat, feat_aug, pB, total, selfp, ap, bar);
    } else {
        (void)hipMemsetAsync(d_ws, 0, 3 * 2048 * sizeof(float), stream);
        infonce_main_slow<<<dim3(256, 32), 256, 0, stream>>>(feat, feat_aug, total, selfp, ap);
    }
    infonce_finalize<<<1, 256, 0, stream>>>(total, selfp, ap, (float*)d_out);
}

// Round 11
// 227.290 us; speedup vs baseline: 1.4717x; 1.4717x over previous
//
#include <hip/hip_runtime.h>
#include <hip/hip_bf16.h>

// Problem: B=8, T=256, V=32, D=256.
// Per-v GEMM: M=N=2048 (rows = i*T+q / j*T+k), K=256, then exp + 3 reductions.
// feature[B,T,V,D]: element (row, v, d) at feat[(row*32 + v)*256 + d].
// v11 = v9 (184.7 us best: B-only repack + in-main A-convert + counted-vmcnt
// sweep) + finalize folded into main via a last-block ticket:
//  - v10 lesson: a grid BARRIER converts block arrival skew into idle time
//    (235 us, MfmaUtil 6%). A last-block TICKET has zero wait by construction:
//    each block threadfences, ACQ_REL fetch_adds a ticket after its atomics;
//    the block drawing 511 (acquire => all others' device-scope atomicAdds
//    visible) reduces total/selfp/ap in-place and writes out. No spin.
//  - Saves one kernel launch + its gap. Repack block 0 zeroes the ticket
//    every replay (stream-ordered before main).
//  - Everything else byte-identical to v9.

typedef __attribute__((ext_vector_type(4))) float f32x4;
typedef __attribute__((ext_vector_type(4))) int   i32x4;
typedef __attribute__((ext_vector_type(8))) int   i32x8;
typedef __attribute__((ext_vector_type(8))) __bf16 bf16x8;   // fallback path

#if __has_builtin(__builtin_amdgcn_exp2f)
#define EXP2(x) __builtin_amdgcn_exp2f(x)
#else
#define EXP2(x) exp2f(x)
#endif

#define LOG2E 1.4426950408889634f

#define WAIT_VMCNT(N)                                              \
    do {                                                           \
        asm volatile("s_waitcnt vmcnt(" #N ")" ::: "memory");      \
        __builtin_amdgcn_sched_barrier(0);                         \
    } while (0)
#define WAIT_LGKM0                                                 \
    do {                                                           \
        asm volatile("s_waitcnt lgkmcnt(0)" ::: "memory");         \
        __builtin_amdgcn_sched_barrier(0);                         \
    } while (0)
#define BARRIER()                                                  \
    do {                                                           \
        __builtin_amdgcn_s_barrier();                              \
        __builtin_amdgcn_sched_barrier(0);                         \
    } while (0)

__device__ __forceinline__ unsigned short f2bf(float f) {
    unsigned u = __builtin_bit_cast(unsigned, f);
    u += 0x7FFFu + ((u >> 16) & 1u);   // RNE (no NaNs in data)
    return (unsigned short)(u >> 16);
}

template <bool HI>
__device__ __forceinline__ unsigned cvt2fp8(float a, float b, unsigned old) {
    return __builtin_amdgcn_cvt_pk_fp8_f32(a, b, old, HI);
}
__device__ __forceinline__ unsigned pack4fp8(float x, float y, float z, float w) {
    return cvt2fp8<true>(z, w, cvt2fp8<false>(x, y, 0u));
}

__device__ __forceinline__ void async16(const void* g, void* l) {
    __builtin_amdgcn_global_load_lds(
        (const __attribute__((address_space(1))) unsigned int*)g,
        (__attribute__((address_space(3))) unsigned int*)l,
        16, 0, 0);
}

__device__ __forceinline__ i32x8 cat8(i32x4 lo, i32x4 hi) {
    i32x8 r;
    r[0] = lo[0]; r[1] = lo[1]; r[2] = lo[2]; r[3] = lo[3];
    r[4] = hi[0]; r[5] = hi[1]; r[6] = hi[2]; r[7] = hi[3];
    return r;
}

// DPP row-sum over 16-lane rows; full sum lands in lane 15 of each row.
template <int CTRL>
__device__ __forceinline__ float dpp_add(float x) {
    int y = __builtin_amdgcn_update_dpp(0, __builtin_bit_cast(int, x),
                                        CTRL, 0xf, 0xf, true);
    return x + __builtin_bit_cast(float, y);
}
__device__ __forceinline__ float rowsum16(float x) {
    x = dpp_add<0x111>(x);   // row_shr:1
    x = dpp_add<0x112>(x);   // row_shr:2
    x = dpp_add<0x114>(x);   // row_shr:4
    x = dpp_add<0x118>(x);   // row_shr:8
    return x;
}

// ------------- repack: streaming fp32 -> fp8 e4m3, B tensor ONLY -------------
// grid (2048): lane-contiguous float4 loads + dword stores, grid-stride x8.
// Block 0 also zeroes the 3*2048 counter floats and the finalize ticket.
__global__ __launch_bounds__(256) void infonce_repack_fp8(
    const float* __restrict__ feat_aug, unsigned char* __restrict__ pB,
    float* __restrict__ counters, unsigned* __restrict__ ticket)
{
    const int tid = threadIdx.x;
    if (blockIdx.x == 0) {
        #pragma unroll
        for (int k = 0; k < 24; ++k) counters[k * 256 + tid] = 0.f;
        if (tid == 0) *ticket = 0u;
    }
    const unsigned g = blockIdx.x * 256u + (unsigned)tid;   // float4 lane slot
    #pragma unroll
    for (int it = 0; it < 8; ++it) {
        const unsigned idx = it * 524288u + g;              // float4 index
        const float4 f = *(const float4*)(feat_aug + (size_t)idx * 4);
        const unsigned p = pack4fp8(f.x, f.y, f.z, f.w);
        *(unsigned*)(pB + (size_t)idx * 4) = p;             // byte i = float i
    }
}

// ----- main: N-sweep MX-fp8 GEMM + exp + reductions, counted-vmcnt pipeline --
// block = (tileM 0..15, v 0..31). A: fp32 staged through a 32 KB LDS buffer
// (4 chunks of 32 rows), converted in-LDS to prescaled fp8 frags in regs.
// B: 2 x [64 rows][256 B] fp8 double buffer. 64 KB LDS, 2 blocks/CU.
// The LAST block (ticket) also performs the finalize reduction -> out.
__global__ __launch_bounds__(256, 2) void infonce_main_nl(
    const float* __restrict__ feat, const unsigned char* __restrict__ pB,
    float* __restrict__ total, float* __restrict__ selfp, float* __restrict__ ap,
    unsigned* __restrict__ ticket, float* __restrict__ out)
{
    __shared__ __align__(16) unsigned char Stage[32 * 1024];   // fp32 A chunks
    __shared__ __align__(16) unsigned char Bs[2][64 * 256];
    // scratch aliases Stage after the final loop barrier (A frags in regs)
    float (*ls_row2)[128]  = (float (*)[128])(void*)Stage;
    float (*ls_self2)[128] = (float (*)[128])(void*)(Stage + 1024);
    float* red4   = (float*)(void*)(Stage + 4096);   // finalize scratch
    int*   lastfl = (int*)(void*)(Stage + 4160);

    const int tid  = threadIdx.x;
    const int lane = tid & 63;
    const int w    = tid >> 6;        // wave 0..3
    const int wm   = w >> 1;          // A rows half
    const int wn   = w & 1;           // B cols half (within 64-col tile)
    const int lrow = lane & 15;
    const int quad = lane >> 4;

    const int tileM = blockIdx.x;     // 0..15
    const int v     = blockIdx.y;     // 0..31
    const int nD0   = (tileM >> 1) * 4;   // first diagonal n-iter

    const size_t vOff = (size_t)v * 256;

    // ---- stage B tiles 0 and 1 first (in flight under A chunk 0) ----
    const size_t rowNbase = (size_t)(w * 16 + quad) * 8192 + vOff;
    #pragma unroll
    for (int nn = 0; nn < 2; ++nn) {
        const unsigned char* srcB = pB + rowNbase + (size_t)nn * 64 * 8192;
        #pragma unroll
        for (int i = 0; i < 4; ++i) {
            const int lg = (lrow ^ ((i * 4 + quad) & 15)) << 4;
            async16(srcB + (size_t)i * 4 * 8192 + lg,
                    &Bs[nn][(w * 16 + i * 4) * 256]);
        }
    }

    // ---- A tile: fp32 -> LDS (coalesced, swizzled) -> fp8 frags in regs ----
    // Chunk c holds tile rows [c*32, c*32+32); serves waves with wm == c>>1,
    // fragments t in {(c&1)*2, (c&1)*2+1}. (v9 path, verified.)
    i32x8 af[2][4];   // [k-half][m-tile]
    #pragma unroll
    for (int c = 0; c < 4; ++c) {
        #pragma unroll
        for (int i = 0; i < 8; ++i) {
            const int rl = w * 8 + i;                     // chunk-local row
            const int gr = tileM * 128 + c * 32 + rl;     // global A row
            const int sg = lane ^ (rl & 15);              // source 16B group
            async16((const unsigned char*)feat +
                        ((size_t)gr * 8192 + vOff + (size_t)sg * 4) * 4,
                    &Stage[rl * 1024 + lane * 16]);
        }
        WAIT_VMCNT(0);     // chunk staged (c==0 also drains B0/B1: harmless)
        BARRIER();
        if ((c >> 1) == wm) {
            #pragma unroll
            for (int tt = 0; tt < 2; ++tt) {
                const int t  = (c & 1) * 2 + tt;          // compile-time
                const int rl = tt * 16 + lrow;            // local row
                #pragma unroll
                for (int h = 0; h < 2; ++h) {
                    i32x8 r;
                    #pragma unroll
                    for (int j = 0; j < 8; ++j) {
                        const int G = h * 32 + quad * 8 + j;   // global group
                        const float4 f = *(const float4*)
                            &Stage[rl * 1024 + ((G ^ lrow) * 16)];
                        r[j] = pack4fp8(f.x * LOG2E, f.y * LOG2E,
                                        f.z * LOG2E, f.w * LOG2E);
                    }
                    af[h][t] = r;
                }
            }
        }
        WAIT_LGKM0;        // my Stage reads done before next chunk overwrites
        BARRIER();
    }

    float rowp[4][4];   // row partials, all n
    float selfr[4][4];  // row partials, diagonal n only
    #pragma unroll
    for (int t = 0; t < 4; ++t)
        #pragma unroll
        for (int r = 0; r < 4; ++r) { rowp[t][r] = 0.f; selfr[t][r] = 0.f; }

    // Per-iteration body AFTER the vmcnt gate. Block-uniform branches only.
    auto iterBody = [&](const int n) {
        const int b = n & 1;
        BARRIER();                      // all waves: Bs[b] contents valid

        // ---- read ALL B fragments of this tile (8 x ds_read_b128) ----
        i32x8 bfr[2][2];                // [k-half][tj]
        #pragma unroll
        for (int h = 0; h < 2; ++h)
            #pragma unroll
            for (int tj = 0; tj < 2; ++tj) {
                const int rB = (wn * 32 + tj * 16 + lrow) * 256;
                const int g0 = ((h * 8 + quad * 2) ^ lrow) * 16;
                bfr[h][tj] = cat8(*(const i32x4*)&Bs[b][rB + g0],
                                  *(const i32x4*)&Bs[b][rB + (g0 ^ 16)]);
            }
        WAIT_LGKM0;                     // my reads of Bs[b] complete
        BARRIER();                      // everyone's reads done -> overwritable

        if (n < 30) {                   // stage tile n+2 into Bs[b]
            const unsigned char* src = pB + rowNbase + (size_t)(n + 2) * 64 * 8192;
            #pragma unroll
            for (int i = 0; i < 4; ++i) {
                const int lg = (lrow ^ ((i * 4 + quad) & 15)) << 4;
                async16(src + (size_t)i * 4 * 8192 + lg,
                        &Bs[b][(w * 16 + i * 4) * 256]);
            }
        }

        // ---- MFMA (regs only) ----
        f32x4 acc[4][2];
        #pragma unroll
        for (int t = 0; t < 4; ++t)
            #pragma unroll
            for (int tj = 0; tj < 2; ++tj)
                acc[t][tj] = (f32x4){0.f, 0.f, 0.f, 0.f};
        __builtin_amdgcn_s_setprio(1);
        #pragma unroll
        for (int h = 0; h < 2; ++h)
            #pragma unroll
            for (int ti = 0; ti < 4; ++ti)
                #pragma unroll
                for (int tj = 0; tj < 2; ++tj)
                    acc[ti][tj] = __builtin_amdgcn_mfma_scale_f32_16x16x128_f8f6f4(
                        af[h][ti], bfr[h][tj], acc[ti][tj],
                        0, 0, 0, 127, 0, 127);   // fp8/fp8, unit E8M0 scales
        __builtin_amdgcn_s_setprio(0);

        // ---- epilogue-accumulate: E = exp2(acc) (A prescaled by log2 e) ----
        const bool diagIter = (n >= nD0) && (n < nD0 + 4);
        float colp0 = 0.f, colp1 = 0.f;
        #pragma unroll
        for (int t = 0; t < 4; ++t)
            #pragma unroll
            for (int r = 0; r < 4; ++r) {
                float e0 = EXP2(acc[t][0][r]);
                float e1 = EXP2(acc[t][1][r]);
                rowp[t][r] += e0 + e1;
                if (diagIter) { selfr[t][r] += e0 + e1; colp0 += e0; colp1 += e1; }
            }
        if (diagIter) {   // col sums -> ap (wave-uniform branch, 4 of 32 iters)
            float q0 = colp0, q1 = colp1;
            q0 += __shfl_xor(q0, 16); q0 += __shfl_xor(q0, 32);
            q1 += __shfl_xor(q1, 16); q1 += __shfl_xor(q1, 32);
            if (lane < 16) {
                atomicAdd(&ap[n * 64 + wn * 32 + lane], q0);
                atomicAdd(&ap[n * 64 + wn * 32 + 16 + lane], q1);
            }
        }
        // no per-iter vmcnt drain: next iter's WAIT_VMCNT is the only gate
    };

    for (int n = 0; n < 31; ++n) {
        // Steady state: outstanding = tiles n (issued at n-2) + n+1 (at n-1);
        // wait(4) -> tile n landed. Iters 0/1: prologue already drained B0/B1.
        WAIT_VMCNT(4);
        iterBody(n);
    }
    WAIT_VMCNT(0);       // last tile: drain everything
    iterBody(31);

    // ---- final row reductions: DPP over the 16 cols held per lane-row ----
    #pragma unroll
    for (int t = 0; t < 4; ++t)
        #pragma unroll
        for (int r = 0; r < 4; ++r) {
            float rs = rowsum16(rowp[t][r]);
            float ss = rowsum16(selfr[t][r]);
            if (lrow == 15) {
                const int idx = wm * 64 + t * 16 + quad * 4 + r;
                ls_row2[wn][idx]  = rs;
                ls_self2[wn][idx] = ss;
            }
        }
    __syncthreads();
    if (tid < 128) {
        atomicAdd(&total[tileM * 128 + tid], ls_row2[0][tid] + ls_row2[1][tid]);
    } else {
        const int t2 = tid - 128;
        atomicAdd(&selfp[tileM * 128 + t2], ls_self2[0][t2] + ls_self2[1][t2]);
    }

    // ---- last-block finalize (ticket; no spin, no waiting) ----
    __threadfence();          // release my atomicAdds device-wide
    __syncthreads();          // all waves of this block issued + fenced
    if (tid == 0) {
        const unsigned old = __hip_atomic_fetch_add(
            ticket, 1u, __ATOMIC_ACQ_REL, __HIP_MEMORY_SCOPE_AGENT);
        *lastfl = (old == 511u) ? 1 : 0;
    }
    __syncthreads();
    if (*lastfl) {
        // acquire side of the ACQ_REL RMW: all 511 other blocks' device-scope
        // atomics to total/selfp/ap are visible. Plain loads OK post-fence.
        __threadfence();
        float s = 0.f;
        for (int e = tid; e < 2048; e += 256) {
            const float an = total[e] - selfp[e];
            s += logf(an / ap[e]);
        }
        #pragma unroll
        for (int m = 32; m >= 1; m >>= 1) s += __shfl_xor(s, m);
        if ((tid & 63) == 0) red4[tid >> 6] = s;
        __syncthreads();
        if (tid == 0)
            out[0] = (red4[0] + red4[1] + red4[2] + red4[3]) * (1.0f / 256.0f);
    }
}

// ---------------- fallback main (round-1 kernel, fp32 staging) ---------------
__global__ __launch_bounds__(256) void infonce_main_slow(
    const float* __restrict__ feat, const float* __restrict__ feat_aug,
    float* __restrict__ total, float* __restrict__ selfp, float* __restrict__ ap)
{
    __shared__ __align__(16) unsigned short As[128][72];
    __shared__ __align__(16) unsigned short Bs[128][72];
    __shared__ float ls_row[128];
    __shared__ float ls_col[128];

    const int tid  = threadIdx.x;
    const int lane = tid & 63;
    const int w    = tid >> 6;
    const int wm   = w >> 1;
    const int wn   = w & 1;
    const int lrow = lane & 15;
    const int quad = lane >> 4;

    const int tileM = blockIdx.x & 15;
    const int tileN = blockIdx.x >> 4;
    const int v     = blockIdx.y;
    const bool diag = (tileM >> 1) == (tileN >> 1);

    if (tid < 128) ls_row[tid] = 0.0f;
    else           ls_col[tid - 128] = 0.0f;

    const float* aBase = feat     + (size_t)v * 256;
    const float* bBase = feat_aug + (size_t)v * 256;

    f32x4 acc[4][4];
    #pragma unroll
    for (int i = 0; i < 4; ++i)
        #pragma unroll
        for (int j = 0; j < 4; ++j)
            acc[i][j] = (f32x4){0.f, 0.f, 0.f, 0.f};

    const int srow = tid >> 4;
    const int scol = (tid & 15) * 4;

    for (int s = 0; s < 4; ++s) {
        const int k0 = s * 64;
        if (s) __syncthreads();
        #pragma unroll
        for (int it = 0; it < 8; ++it) {
            const int row = it * 16 + srow;
            const float4 a4 = *(const float4*)(aBase + (size_t)(tileM * 128 + row) * 8192 + k0 + scol);
            const float4 b4 = *(const float4*)(bBase + (size_t)(tileN * 128 + row) * 8192 + k0 + scol);
            uint2 wa, wb;
            wa.x = (unsigned)f2bf(a4.x) | ((unsigned)f2bf(a4.y) << 16);
            wa.y = (unsigned)f2bf(a4.z) | ((unsigned)f2bf(a4.w) << 16);
            wb.x = (unsigned)f2bf(b4.x) | ((unsigned)f2bf(b4.y) << 16);
            wb.y = (unsigned)f2bf(b4.z) | ((unsigned)f2bf(b4.w) << 16);
            *(uint2*)&As[row][scol] = wa;
            *(uint2*)&Bs[row][scol] = wb;
        }
        __syncthreads();
        #pragma unroll
        for (int kk = 0; kk < 64; kk += 32) {
            bf16x8 af[4], bfr[4];
            #pragma unroll
            for (int t = 0; t < 4; ++t) {
                af[t]  = *(const bf16x8*)&As[wm * 64 + t * 16 + lrow][kk + quad * 8];
                bfr[t] = *(const bf16x8*)&Bs[wn * 64 + t * 16 + lrow][kk + quad * 8];
            }
            #pragma unroll
            for (int ti = 0; ti < 4; ++ti)
                #pragma unroll
                for (int tj = 0; tj < 4; ++tj)
                    acc[ti][tj] = __builtin_amdgcn_mfma_f32_16x16x32_bf16(
                        af[ti], bfr[tj], acc[ti][tj], 0, 0, 0);
        }
    }

    float colp[4] = {0.f, 0.f, 0.f, 0.f};
    #pragma unroll
    for (int ti = 0; ti < 4; ++ti) {
        #pragma unroll
        for (int r = 0; r < 4; ++r) {
            float e0 = __expf(acc[ti][0][r]);
            float e1 = __expf(acc[ti][1][r]);
            float e2 = __expf(acc[ti][2][r]);
            float e3 = __expf(acc[ti][3][r]);
            colp[0] += e0; colp[1] += e1; colp[2] += e2; colp[3] += e3;
            float rp = (e0 + e1) + (e2 + e3);
            rp += __shfl_xor(rp, 1);
            rp += __shfl_xor(rp, 2);
            rp += __shfl_xor(rp, 4);
            rp += __shfl_xor(rp, 8);
            if (lrow == 0)
                atomicAdd(&ls_row[wm * 64 + ti * 16 + quad * 4 + r], rp);
        }
    }
    if (diag) {
        #pragma unroll
        for (int tj = 0; tj < 4; ++tj) {
            float q = colp[tj];
            q += __shfl_xor(q, 16);
            q += __shfl_xor(q, 32);
            if (lane < 16)
                atomicAdd(&ls_col[wn * 64 + tj * 16 + lane], q);
        }
    }
    __syncthreads();
    if (tid < 128) {
        const float rs = ls_row[tid];
        const int rowg = tileM * 128 + tid;
        atomicAdd(&total[rowg], rs);
        if (diag) atomicAdd(&selfp[rowg], rs);
    } else if (diag) {
        const int t2 = tid - 128;
        atomicAdd(&ap[tileN * 128 + t2], ls_col[t2]);
    }
}

__global__ __launch_bounds__(256) void infonce_finalize(
    const float* __restrict__ total, const float* __restrict__ selfp,
    const float* __restrict__ ap, float* __restrict__ out)
{
    __shared__ float red[4];
    const int tid = threadIdx.x;
    float s = 0.f;
    for (int e = tid; e < 2048; e += 256) {
        const float an = total[e] - selfp[e];
        s += logf(an / ap[e]);
    }
    #pragma unroll
    for (int m = 32; m >= 1; m >>= 1) s += __shfl_xor(s, m);
    if ((tid & 63) == 0) red[tid >> 6] = s;
    __syncthreads();
    if (tid == 0) out[0] = (red[0] + red[1] + red[2] + red[3]) * (1.0f / 256.0f);
}

extern "C" void kernel_launch(void* const* d_in, const int* in_sizes, int n_in,
                              void* d_out, int out_size, void* d_ws, size_t ws_size,
                              hipStream_t stream) {
    const float* feat     = (const float*)d_in[0];
    const float* feat_aug = (const float*)d_in[1];
    float* total = (float*)d_ws;
    float* selfp = total + 2048;
    float* ap    = selfp + 2048;
    unsigned* ticket = (unsigned*)(ap + 2048);

    const size_t packBytes = (size_t)2048 * 8192;                  // B tensor, fp8
    const size_t need = 32768 + packBytes;
    if (ws_size >= need) {
        unsigned char* pB = (unsigned char*)d_ws + 32768;
        infonce_repack_fp8<<<dim3(2048), 256, 0, stream>>>(feat_aug, pB, total, ticket);
        infonce_main_nl<<<dim3(16, 32), 256, 0, stream>>>(
            feat, pB, total, selfp, ap, ticket, (float*)d_out);
    } else {
        (void)hipMemsetAsync(d_ws, 0, 3 * 2048 * sizeof(float), stream);
        infonce_main_slow<<<dim3(256, 32), 256, 0, stream>>>(feat, feat_aug, total, selfp, ap);
        infonce_finalize<<<1, 256, 0, stream>>>(total, selfp, ap, (float*)d_out);
    }
}

// Round 12
// 184.652 us; speedup vs baseline: 1.8115x; 1.2309x over previous
//
#include <hip/hip_runtime.h>
#include <hip/hip_bf16.h>

// Problem: B=8, T=256, V=32, D=256.
// Per-v GEMM: M=N=2048 (rows = i*T+q / j*T+k), K=256, then exp + 3 reductions.
// feature[B,T,V,D]: element (row, v, d) at feat[(row*32 + v)*256 + d].
// v12 = clean revert to v9 (184.7 us, session best), byte-for-byte:
//  - B-only repack (lane-contiguous float4 -> pack4fp8 -> dword).
//  - main: A fp32 staged via coalesced async16 into 32 KB LDS (4 chunks),
//    converted in-LDS to prescaled fp8 frags in regs; B double-buffered
//    counted-vmcnt N-sweep (s_barrier + vmcnt(4), never 0 mid-loop).
//  - separate finalize kernel.
// v10 lesson: grid barrier converts arrival skew into idle (235 us).
// v11 lesson: per-block device-scope __threadfence() = L2 writeback that
// trashes cache for all resident blocks (main 63 -> 110 us). Both reverted.

typedef __attribute__((ext_vector_type(4))) float f32x4;
typedef __attribute__((ext_vector_type(4))) int   i32x4;
typedef __attribute__((ext_vector_type(8))) int   i32x8;
typedef __attribute__((ext_vector_type(8))) __bf16 bf16x8;   // fallback path

#if __has_builtin(__builtin_amdgcn_exp2f)
#define EXP2(x) __builtin_amdgcn_exp2f(x)
#else
#define EXP2(x) exp2f(x)
#endif

#define LOG2E 1.4426950408889634f

#define WAIT_VMCNT(N)                                              \
    do {                                                           \
        asm volatile("s_waitcnt vmcnt(" #N ")" ::: "memory");      \
        __builtin_amdgcn_sched_barrier(0);                         \
    } while (0)
#define WAIT_LGKM0                                                 \
    do {                                                           \
        asm volatile("s_waitcnt lgkmcnt(0)" ::: "memory");         \
        __builtin_amdgcn_sched_barrier(0);                         \
    } while (0)
#define BARRIER()                                                  \
    do {                                                           \
        __builtin_amdgcn_s_barrier();                              \
        __builtin_amdgcn_sched_barrier(0);                         \
    } while (0)

__device__ __forceinline__ unsigned short f2bf(float f) {
    unsigned u = __builtin_bit_cast(unsigned, f);
    u += 0x7FFFu + ((u >> 16) & 1u);   // RNE (no NaNs in data)
    return (unsigned short)(u >> 16);
}

template <bool HI>
__device__ __forceinline__ unsigned cvt2fp8(float a, float b, unsigned old) {
    return __builtin_amdgcn_cvt_pk_fp8_f32(a, b, old, HI);
}
__device__ __forceinline__ unsigned pack4fp8(float x, float y, float z, float w) {
    return cvt2fp8<true>(z, w, cvt2fp8<false>(x, y, 0u));
}

__device__ __forceinline__ void async16(const void* g, void* l) {
    __builtin_amdgcn_global_load_lds(
        (const __attribute__((address_space(1))) unsigned int*)g,
        (__attribute__((address_space(3))) unsigned int*)l,
        16, 0, 0);
}

__device__ __forceinline__ i32x8 cat8(i32x4 lo, i32x4 hi) {
    i32x8 r;
    r[0] = lo[0]; r[1] = lo[1]; r[2] = lo[2]; r[3] = lo[3];
    r[4] = hi[0]; r[5] = hi[1]; r[6] = hi[2]; r[7] = hi[3];
    return r;
}

// DPP row-sum over 16-lane rows; full sum lands in lane 15 of each row.
template <int CTRL>
__device__ __forceinline__ float dpp_add(float x) {
    int y = __builtin_amdgcn_update_dpp(0, __builtin_bit_cast(int, x),
                                        CTRL, 0xf, 0xf, true);
    return x + __builtin_bit_cast(float, y);
}
__device__ __forceinline__ float rowsum16(float x) {
    x = dpp_add<0x111>(x);   // row_shr:1
    x = dpp_add<0x112>(x);   // row_shr:2
    x = dpp_add<0x114>(x);   // row_shr:4
    x = dpp_add<0x118>(x);   // row_shr:8
    return x;
}

// ------------- repack: streaming fp32 -> fp8 e4m3, B tensor ONLY -------------
// grid (2048): lane-contiguous float4 loads + dword stores, grid-stride x8.
// Block 0 also zeroes the 3*2048 counter floats (replaces memset dispatch).
__global__ __launch_bounds__(256) void infonce_repack_fp8(
    const float* __restrict__ feat_aug, unsigned char* __restrict__ pB,
    float* __restrict__ counters)
{
    const int tid = threadIdx.x;
    if (blockIdx.x == 0) {
        #pragma unroll
        for (int k = 0; k < 24; ++k) counters[k * 256 + tid] = 0.f;
    }
    const unsigned g = blockIdx.x * 256u + (unsigned)tid;   // float4 lane slot
    #pragma unroll
    for (int it = 0; it < 8; ++it) {
        const unsigned idx = it * 524288u + g;              // float4 index
        const float4 f = *(const float4*)(feat_aug + (size_t)idx * 4);
        const unsigned p = pack4fp8(f.x, f.y, f.z, f.w);
        *(unsigned*)(pB + (size_t)idx * 4) = p;             // byte i = float i
    }
}

// ----- main: N-sweep MX-fp8 GEMM + exp + reductions, counted-vmcnt pipeline --
// block = (tileM 0..15, v 0..31). A: fp32 staged through a 32 KB LDS buffer
// (4 chunks of 32 rows), converted in-LDS to prescaled fp8 frags in regs.
// B: 2 x [64 rows][256 B] fp8 double buffer. 64 KB LDS, 2 blocks/CU.
__global__ __launch_bounds__(256, 2) void infonce_main_nl(
    const float* __restrict__ feat, const unsigned char* __restrict__ pB,
    float* __restrict__ total, float* __restrict__ selfp, float* __restrict__ ap)
{
    __shared__ __align__(16) unsigned char Stage[32 * 1024];   // fp32 A chunks
    __shared__ __align__(16) unsigned char Bs[2][64 * 256];
    // scratch aliases Stage after the final loop barrier (A frags in regs)
    float (*ls_row2)[128]  = (float (*)[128])(void*)Stage;
    float (*ls_self2)[128] = (float (*)[128])(void*)(Stage + 1024);

    const int tid  = threadIdx.x;
    const int lane = tid & 63;
    const int w    = tid >> 6;        // wave 0..3
    const int wm   = w >> 1;          // A rows half
    const int wn   = w & 1;           // B cols half (within 64-col tile)
    const int lrow = lane & 15;
    const int quad = lane >> 4;

    const int tileM = blockIdx.x;     // 0..15
    const int v     = blockIdx.y;     // 0..31
    const int nD0   = (tileM >> 1) * 4;   // first diagonal n-iter

    const size_t vOff = (size_t)v * 256;

    // ---- stage B tiles 0 and 1 first (in flight under A chunk 0) ----
    const size_t rowNbase = (size_t)(w * 16 + quad) * 8192 + vOff;
    #pragma unroll
    for (int nn = 0; nn < 2; ++nn) {
        const unsigned char* srcB = pB + rowNbase + (size_t)nn * 64 * 8192;
        #pragma unroll
        for (int i = 0; i < 4; ++i) {
            const int lg = (lrow ^ ((i * 4 + quad) & 15)) << 4;
            async16(srcB + (size_t)i * 4 * 8192 + lg,
                    &Bs[nn][(w * 16 + i * 4) * 256]);
        }
    }

    // ---- A tile: fp32 -> LDS (coalesced, swizzled) -> fp8 frags in regs ----
    // Chunk c holds tile rows [c*32, c*32+32); serves waves with wm == c>>1,
    // fragments t in {(c&1)*2, (c&1)*2+1}. LDS 16B-group p of local row rl
    // holds global group p ^ (rl & 15) (source pre-swizzle) so the fragment
    // read (group G at position G ^ lrow) is low-conflict.
    i32x8 af[2][4];   // [k-half][m-tile]
    #pragma unroll
    for (int c = 0; c < 4; ++c) {
        #pragma unroll
        for (int i = 0; i < 8; ++i) {
            const int rl = w * 8 + i;                     // chunk-local row
            const int gr = tileM * 128 + c * 32 + rl;     // global A row
            const int sg = lane ^ (rl & 15);              // source 16B group
            async16((const unsigned char*)feat +
                        ((size_t)gr * 8192 + vOff + (size_t)sg * 4) * 4,
                    &Stage[rl * 1024 + lane * 16]);
        }
        WAIT_VMCNT(0);     // chunk staged (c==0 also drains B0/B1: harmless)
        BARRIER();
        if ((c >> 1) == wm) {
            #pragma unroll
            for (int tt = 0; tt < 2; ++tt) {
                const int t  = (c & 1) * 2 + tt;          // compile-time
                const int rl = tt * 16 + lrow;            // local row
                #pragma unroll
                for (int h = 0; h < 2; ++h) {
                    i32x8 r;
                    #pragma unroll
                    for (int j = 0; j < 8; ++j) {
                        const int G = h * 32 + quad * 8 + j;   // global group
                        const float4 f = *(const float4*)
                            &Stage[rl * 1024 + ((G ^ lrow) * 16)];
                        r[j] = pack4fp8(f.x * LOG2E, f.y * LOG2E,
                                        f.z * LOG2E, f.w * LOG2E);
                    }
                    af[h][t] = r;
                }
            }
        }
        WAIT_LGKM0;        // my Stage reads done before next chunk overwrites
        BARRIER();
    }

    float rowp[4][4];   // row partials, all n
    float selfr[4][4];  // row partials, diagonal n only
    #pragma unroll
    for (int t = 0; t < 4; ++t)
        #pragma unroll
        for (int r = 0; r < 4; ++r) { rowp[t][r] = 0.f; selfr[t][r] = 0.f; }

    // Per-iteration body AFTER the vmcnt gate. Block-uniform branches only.
    auto iterBody = [&](const int n) {
        const int b = n & 1;
        BARRIER();                      // all waves: Bs[b] contents valid

        // ---- read ALL B fragments of this tile (8 x ds_read_b128) ----
        i32x8 bfr[2][2];                // [k-half][tj]
        #pragma unroll
        for (int h = 0; h < 2; ++h)
            #pragma unroll
            for (int tj = 0; tj < 2; ++tj) {
                const int rB = (wn * 32 + tj * 16 + lrow) * 256;
                const int g0 = ((h * 8 + quad * 2) ^ lrow) * 16;
                bfr[h][tj] = cat8(*(const i32x4*)&Bs[b][rB + g0],
                                  *(const i32x4*)&Bs[b][rB + (g0 ^ 16)]);
            }
        WAIT_LGKM0;                     // my reads of Bs[b] complete
        BARRIER();                      // everyone's reads done -> overwritable

        if (n < 30) {                   // stage tile n+2 into Bs[b]
            const unsigned char* src = pB + rowNbase + (size_t)(n + 2) * 64 * 8192;
            #pragma unroll
            for (int i = 0; i < 4; ++i) {
                const int lg = (lrow ^ ((i * 4 + quad) & 15)) << 4;
                async16(src + (size_t)i * 4 * 8192 + lg,
                        &Bs[b][(w * 16 + i * 4) * 256]);
            }
        }

        // ---- MFMA (regs only) ----
        f32x4 acc[4][2];
        #pragma unroll
        for (int t = 0; t < 4; ++t)
            #pragma unroll
            for (int tj = 0; tj < 2; ++tj)
                acc[t][tj] = (f32x4){0.f, 0.f, 0.f, 0.f};
        __builtin_amdgcn_s_setprio(1);
        #pragma unroll
        for (int h = 0; h < 2; ++h)
            #pragma unroll
            for (int ti = 0; ti < 4; ++ti)
                #pragma unroll
                for (int tj = 0; tj < 2; ++tj)
                    acc[ti][tj] = __builtin_amdgcn_mfma_scale_f32_16x16x128_f8f6f4(
                        af[h][ti], bfr[h][tj], acc[ti][tj],
                        0, 0, 0, 127, 0, 127);   // fp8/fp8, unit E8M0 scales
        __builtin_amdgcn_s_setprio(0);

        // ---- epilogue-accumulate: E = exp2(acc) (A prescaled by log2 e) ----
        const bool diagIter = (n >= nD0) && (n < nD0 + 4);
        float colp0 = 0.f, colp1 = 0.f;
        #pragma unroll
        for (int t = 0; t < 4; ++t)
            #pragma unroll
            for (int r = 0; r < 4; ++r) {
                float e0 = EXP2(acc[t][0][r]);
                float e1 = EXP2(acc[t][1][r]);
                rowp[t][r] += e0 + e1;
                if (diagIter) { selfr[t][r] += e0 + e1; colp0 += e0; colp1 += e1; }
            }
        if (diagIter) {   // col sums -> ap (wave-uniform branch, 4 of 32 iters)
            float q0 = colp0, q1 = colp1;
            q0 += __shfl_xor(q0, 16); q0 += __shfl_xor(q0, 32);
            q1 += __shfl_xor(q1, 16); q1 += __shfl_xor(q1, 32);
            if (lane < 16) {
                atomicAdd(&ap[n * 64 + wn * 32 + lane], q0);
                atomicAdd(&ap[n * 64 + wn * 32 + 16 + lane], q1);
            }
        }
        // no per-iter vmcnt drain: next iter's WAIT_VMCNT is the only gate
    };

    for (int n = 0; n < 31; ++n) {
        // Steady state: outstanding = tiles n (issued at n-2) + n+1 (at n-1);
        // wait(4) -> tile n landed. Iters 0/1: prologue already drained B0/B1.
        WAIT_VMCNT(4);
        iterBody(n);
    }
    WAIT_VMCNT(0);       // last tile: drain everything
    iterBody(31);

    // ---- final row reductions: DPP over the 16 cols held per lane-row ----
    #pragma unroll
    for (int t = 0; t < 4; ++t)
        #pragma unroll
        for (int r = 0; r < 4; ++r) {
            float rs = rowsum16(rowp[t][r]);
            float ss = rowsum16(selfr[t][r]);
            if (lrow == 15) {
                const int idx = wm * 64 + t * 16 + quad * 4 + r;
                ls_row2[wn][idx]  = rs;
                ls_self2[wn][idx] = ss;
            }
        }
    __syncthreads();
    if (tid < 128) {
        atomicAdd(&total[tileM * 128 + tid], ls_row2[0][tid] + ls_row2[1][tid]);
    } else {
        const int t2 = tid - 128;
        atomicAdd(&selfp[tileM * 128 + t2], ls_self2[0][t2] + ls_self2[1][t2]);
    }
}

// ---------------- fallback main (round-1 kernel, fp32 staging) ---------------
__global__ __launch_bounds__(256) void infonce_main_slow(
    const float* __restrict__ feat, const float* __restrict__ feat_aug,
    float* __restrict__ total, float* __restrict__ selfp, float* __restrict__ ap)
{
    __shared__ __align__(16) unsigned short As[128][72];
    __shared__ __align__(16) unsigned short Bs[128][72];
    __shared__ float ls_row[128];
    __shared__ float ls_col[128];

    const int tid  = threadIdx.x;
    const int lane = tid & 63;
    const int w    = tid >> 6;
    const int wm   = w >> 1;
    const int wn   = w & 1;
    const int lrow = lane & 15;
    const int quad = lane >> 4;

    const int tileM = blockIdx.x & 15;
    const int tileN = blockIdx.x >> 4;
    const int v     = blockIdx.y;
    const bool diag = (tileM >> 1) == (tileN >> 1);

    if (tid < 128) ls_row[tid] = 0.0f;
    else           ls_col[tid - 128] = 0.0f;

    const float* aBase = feat     + (size_t)v * 256;
    const float* bBase = feat_aug + (size_t)v * 256;

    f32x4 acc[4][4];
    #pragma unroll
    for (int i = 0; i < 4; ++i)
        #pragma unroll
        for (int j = 0; j < 4; ++j)
            acc[i][j] = (f32x4){0.f, 0.f, 0.f, 0.f};

    const int srow = tid >> 4;
    const int scol = (tid & 15) * 4;

    for (int s = 0; s < 4; ++s) {
        const int k0 = s * 64;
        if (s) __syncthreads();
        #pragma unroll
        for (int it = 0; it < 8; ++it) {
            const int row = it * 16 + srow;
            const float4 a4 = *(const float4*)(aBase + (size_t)(tileM * 128 + row) * 8192 + k0 + scol);
            const float4 b4 = *(const float4*)(bBase + (size_t)(tileN * 128 + row) * 8192 + k0 + scol);
            uint2 wa, wb;
            wa.x = (unsigned)f2bf(a4.x) | ((unsigned)f2bf(a4.y) << 16);
            wa.y = (unsigned)f2bf(a4.z) | ((unsigned)f2bf(a4.w) << 16);
            wb.x = (unsigned)f2bf(b4.x) | ((unsigned)f2bf(b4.y) << 16);
            wb.y = (unsigned)f2bf(b4.z) | ((unsigned)f2bf(b4.w) << 16);
            *(uint2*)&As[row][scol] = wa;
            *(uint2*)&Bs[row][scol] = wb;
        }
        __syncthreads();
        #pragma unroll
        for (int kk = 0; kk < 64; kk += 32) {
            bf16x8 af[4], bfr[4];
            #pragma unroll
            for (int t = 0; t < 4; ++t) {
                af[t]  = *(const bf16x8*)&As[wm * 64 + t * 16 + lrow][kk + quad * 8];
                bfr[t] = *(const bf16x8*)&Bs[wn * 64 + t * 16 + lrow][kk + quad * 8];
            }
            #pragma unroll
            for (int ti = 0; ti < 4; ++ti)
                #pragma unroll
                for (int tj = 0; tj < 4; ++tj)
                    acc[ti][tj] = __builtin_amdgcn_mfma_f32_16x16x32_bf16(
                        af[ti], bfr[tj], acc[ti][tj], 0, 0, 0);
        }
    }

    float colp[4] = {0.f, 0.f, 0.f, 0.f};
    #pragma unroll
    for (int ti = 0; ti < 4; ++ti) {
        #pragma unroll
        for (int r = 0; r < 4; ++r) {
            float e0 = __expf(acc[ti][0][r]);
            float e1 = __expf(acc[ti][1][r]);
            float e2 = __expf(acc[ti][2][r]);
            float e3 = __expf(acc[ti][3][r]);
            colp[0] += e0; colp[1] += e1; colp[2] += e2; colp[3] += e3;
            float rp = (e0 + e1) + (e2 + e3);
            rp += __shfl_xor(rp, 1);
            rp += __shfl_xor(rp, 2);
            rp += __shfl_xor(rp, 4);
            rp += __shfl_xor(rp, 8);
            if (lrow == 0)
                atomicAdd(&ls_row[wm * 64 + ti * 16 + quad * 4 + r], rp);
        }
    }
    if (diag) {
        #pragma unroll
        for (int tj = 0; tj < 4; ++tj) {
            float q = colp[tj];
            q += __shfl_xor(q, 16);
            q += __shfl_xor(q, 32);
            if (lane < 16)
                atomicAdd(&ls_col[wn * 64 + tj * 16 + lane], q);
        }
    }
    __syncthreads();
    if (tid < 128) {
        const float rs = ls_row[tid];
        const int rowg = tileM * 128 + tid;
        atomicAdd(&total[rowg], rs);
        if (diag) atomicAdd(&selfp[rowg], rs);
    } else if (diag) {
        const int t2 = tid - 128;
        atomicAdd(&ap[tileN * 128 + t2], ls_col[t2]);
    }
}

__global__ __launch_bounds__(256) void infonce_finalize(
    const float* __restrict__ total, const float* __restrict__ selfp,
    const float* __restrict__ ap, float* __restrict__ out)
{
    __shared__ float red[4];
    const int tid = threadIdx.x;
    float s = 0.f;
    for (int e = tid; e < 2048; e += 256) {
        const float an = total[e] - selfp[e];
        s += logf(an / ap[e]);
    }
    #pragma unroll
    for (int m = 32; m >= 1; m >>= 1) s += __shfl_xor(s, m);
    if ((tid & 63) == 0) red[tid >> 6] = s;
    __syncthreads();
    if (tid == 0) out[0] = (red[0] + red[1] + red[2] + red[3]) * (1.0f / 256.0f);
}

extern "C" void kernel_launch(void* const* d_in, const int* in_sizes, int n_in,
                              void* d_out, int out_size, void* d_ws, size_t ws_size,
                              hipStream_t stream) {
    const float* feat     = (const float*)d_in[0];
    const float* feat_aug = (const float*)d_in[1];
    float* total = (float*)d_ws;
    float* selfp = total + 2048;
    float* ap    = selfp + 2048;

    const size_t packBytes = (size_t)2048 * 8192;                  // B tensor, fp8
    const size_t need = 32768 + packBytes;
    if (ws_size >= need) {
        unsigned char* pB = (unsigned char*)d_ws + 32768;
        infonce_repack_fp8<<<dim3(2048), 256, 0, stream>>>(feat_aug, pB, total);
        infonce_main_nl<<<dim3(16, 32), 256, 0, stream>>>(feat, pB, total, selfp, ap);
    } else {
        (void)hipMemsetAsync(d_ws, 0, 3 * 2048 * sizeof(float), stream);
        infonce_main_slow<<<dim3(256, 32), 256, 0, stream>>>(feat, feat_aug, total, selfp, ap);
    }
    infonce_finalize<<<1, 256, 0, stream>>>(total, selfp, ap, (float*)d_out);
}